// Round 1
// baseline (25.595 us; speedup 1.0000x reference)
//
#include <hip/hip_runtime.h>

// N=65536 rows, D=256 fp32. out[row] = -dot(q[row], d[row]).
// One wave (64 lanes) per row: lane i loads float4 at element 4*i -> exactly
// covers D=256. Coalesced 16B/lane, then 6-step shuffle reduce over 64 lanes.

__global__ __launch_bounds__(256) void neg_rowdot_kernel(
    const float* __restrict__ q,
    const float* __restrict__ d,
    float* __restrict__ out,
    int n_rows)
{
    const int lane        = threadIdx.x & 63;
    const int wave_in_blk = threadIdx.x >> 6;          // 0..3
    const int waves_per_blk = blockDim.x >> 6;         // 4
    int row = blockIdx.x * waves_per_blk + wave_in_blk;
    const int row_stride = gridDim.x * waves_per_blk;

    for (; row < n_rows; row += row_stride) {
        const float4* q4 = reinterpret_cast<const float4*>(q + (size_t)row * 256);
        const float4* d4 = reinterpret_cast<const float4*>(d + (size_t)row * 256);
        float4 a = q4[lane];
        float4 b = d4[lane];
        float s = a.x * b.x + a.y * b.y + a.z * b.z + a.w * b.w;

        // wave-64 butterfly-free down-reduce
        s += __shfl_down(s, 32, 64);
        s += __shfl_down(s, 16, 64);
        s += __shfl_down(s,  8, 64);
        s += __shfl_down(s,  4, 64);
        s += __shfl_down(s,  2, 64);
        s += __shfl_down(s,  1, 64);

        if (lane == 0) out[row] = -s;
    }
}

extern "C" void kernel_launch(void* const* d_in, const int* in_sizes, int n_in,
                              void* d_out, int out_size, void* d_ws, size_t ws_size,
                              hipStream_t stream) {
    const float* q = (const float*)d_in[0];
    const float* d = (const float*)d_in[1];
    float* out = (float*)d_out;

    const int n_rows = out_size;              // 65536
    const int block = 256;                    // 4 waves/block
    const int waves_per_blk = block / 64;
    int grid = (n_rows + waves_per_blk - 1) / waves_per_blk;  // 16384
    if (grid > 2048) grid = 2048;             // 256 CU x 8 blocks, grid-stride rest

    neg_rowdot_kernel<<<grid, block, 0, stream>>>(q, d, out, n_rows);
}

// Round 2
// 24.418 us; speedup vs baseline: 1.0482x; 1.0482x over previous
//
#include <hip/hip_runtime.h>

// N=65536 rows, D=256 fp32. out[row] = -dot(q[row], d[row]).
//
// 4 rows per wave, 16 lanes per row. Each lane issues 8 independent float4
// loads up-front (4 for q, 4 for d) -> deep MLP, then 32 FMAs and a 4-step
// shuffle reduction confined to its 16-lane group (reduces all 4 rows of the
// wave simultaneously). One-shot grid: 16 rows/block x 4096 blocks, no loop.

__global__ __launch_bounds__(256) void neg_rowdot_kernel(
    const float* __restrict__ q,
    const float* __restrict__ d,
    float* __restrict__ out)
{
    const int lane = threadIdx.x & 63;
    const int wave = threadIdx.x >> 6;     // 0..3
    const int sub  = lane >> 4;            // row within wave's 4: 0..3
    const int c    = lane & 15;            // 16-lane column group

    const int row = blockIdx.x * 16 + wave * 4 + sub;

    const float4* q4 = reinterpret_cast<const float4*>(q) + (size_t)row * 64;
    const float4* d4 = reinterpret_cast<const float4*>(d) + (size_t)row * 64;

    // 8 independent loads, all in flight before any use.
    float4 a0 = q4[c];
    float4 a1 = q4[c + 16];
    float4 a2 = q4[c + 32];
    float4 a3 = q4[c + 48];
    float4 b0 = d4[c];
    float4 b1 = d4[c + 16];
    float4 b2 = d4[c + 32];
    float4 b3 = d4[c + 48];

    float s0 = a0.x * b0.x + a0.y * b0.y + a0.z * b0.z + a0.w * b0.w;
    float s1 = a1.x * b1.x + a1.y * b1.y + a1.z * b1.z + a1.w * b1.w;
    float s2 = a2.x * b2.x + a2.y * b2.y + a2.z * b2.z + a2.w * b2.w;
    float s3 = a3.x * b3.x + a3.y * b3.y + a3.z * b3.z + a3.w * b3.w;
    float s = (s0 + s1) + (s2 + s3);

    // Reduce across the 16 lanes of this row (xor masks < 16 stay in-group).
    s += __shfl_xor(s, 8, 64);
    s += __shfl_xor(s, 4, 64);
    s += __shfl_xor(s, 2, 64);
    s += __shfl_xor(s, 1, 64);

    if (c == 0) out[row] = -s;
}

extern "C" void kernel_launch(void* const* d_in, const int* in_sizes, int n_in,
                              void* d_out, int out_size, void* d_ws, size_t ws_size,
                              hipStream_t stream) {
    const float* q = (const float*)d_in[0];
    const float* d = (const float*)d_in[1];
    float* out = (float*)d_out;

    const int n_rows = out_size;                  // 65536
    const int rows_per_block = 16;                // 4 waves x 4 rows
    int grid = n_rows / rows_per_block;           // 4096

    neg_rowdot_kernel<<<grid, 256, 0, stream>>>(q, d, out);
}

// Round 3
// 24.314 us; speedup vs baseline: 1.0527x; 1.0043x over previous
//
#include <hip/hip_runtime.h>

// N=65536 rows, D=256 fp32. out[row] = -dot(q[row], d[row]).
//
// 8 rows per wave, 16 lanes per row, two row-groups of 4. Each lane issues
// ALL 16 independent float4 loads up-front (256 B/lane in flight -> deep MLP),
// then FMAs and two 4-step shuffle reductions confined to its 16-lane group.
// One-shot grid: 32 rows/block x 2048 blocks.

__global__ __launch_bounds__(256) void neg_rowdot_kernel(
    const float* __restrict__ q,
    const float* __restrict__ d,
    float* __restrict__ out)
{
    const int lane = threadIdx.x & 63;
    const int wave = threadIdx.x >> 6;     // 0..3
    const int sub  = lane >> 4;            // 0..3
    const int c    = lane & 15;            // 16-lane column group

    const int base_row = blockIdx.x * 32 + wave * 8;
    const int rowA = base_row + sub;       // pass A rows
    const int rowB = base_row + 4 + sub;   // pass B rows

    const float4* qA = reinterpret_cast<const float4*>(q) + (size_t)rowA * 64;
    const float4* dA = reinterpret_cast<const float4*>(d) + (size_t)rowA * 64;
    const float4* qB = reinterpret_cast<const float4*>(q) + (size_t)rowB * 64;
    const float4* dB = reinterpret_cast<const float4*>(d) + (size_t)rowB * 64;

    // 16 independent loads, all in flight before any use.
    float4 a0 = qA[c];
    float4 a1 = qA[c + 16];
    float4 a2 = qA[c + 32];
    float4 a3 = qA[c + 48];
    float4 b0 = dA[c];
    float4 b1 = dA[c + 16];
    float4 b2 = dA[c + 32];
    float4 b3 = dA[c + 48];
    float4 e0 = qB[c];
    float4 e1 = qB[c + 16];
    float4 e2 = qB[c + 32];
    float4 e3 = qB[c + 48];
    float4 f0 = dB[c];
    float4 f1 = dB[c + 16];
    float4 f2 = dB[c + 32];
    float4 f3 = dB[c + 48];

    float sa0 = a0.x * b0.x + a0.y * b0.y + a0.z * b0.z + a0.w * b0.w;
    float sa1 = a1.x * b1.x + a1.y * b1.y + a1.z * b1.z + a1.w * b1.w;
    float sa2 = a2.x * b2.x + a2.y * b2.y + a2.z * b2.z + a2.w * b2.w;
    float sa3 = a3.x * b3.x + a3.y * b3.y + a3.z * b3.z + a3.w * b3.w;
    float sa = (sa0 + sa1) + (sa2 + sa3);

    float sb0 = e0.x * f0.x + e0.y * f0.y + e0.z * f0.z + e0.w * f0.w;
    float sb1 = e1.x * f1.x + e1.y * f1.y + e1.z * f1.z + e1.w * f1.w;
    float sb2 = e2.x * f2.x + e2.y * f2.y + e2.z * f2.z + e2.w * f2.w;
    float sb3 = e3.x * f3.x + e3.y * f3.y + e3.z * f3.z + e3.w * f3.w;
    float sb = (sb0 + sb1) + (sb2 + sb3);

    // Reduce within the 16-lane group (xor masks < 16 stay in-group).
    sa += __shfl_xor(sa, 8, 64);
    sb += __shfl_xor(sb, 8, 64);
    sa += __shfl_xor(sa, 4, 64);
    sb += __shfl_xor(sb, 4, 64);
    sa += __shfl_xor(sa, 2, 64);
    sb += __shfl_xor(sb, 2, 64);
    sa += __shfl_xor(sa, 1, 64);
    sb += __shfl_xor(sb, 1, 64);

    if (c == 0) {
        out[rowA] = -sa;
        out[rowB] = -sb;
    }
}

extern "C" void kernel_launch(void* const* d_in, const int* in_sizes, int n_in,
                              void* d_out, int out_size, void* d_ws, size_t ws_size,
                              hipStream_t stream) {
    const float* q = (const float*)d_in[0];
    const float* d = (const float*)d_in[1];
    float* out = (float*)d_out;

    const int n_rows = out_size;                  // 65536
    const int rows_per_block = 32;                // 4 waves x 8 rows
    int grid = n_rows / rows_per_block;           // 2048

    neg_rowdot_kernel<<<grid, 256, 0, stream>>>(q, d, out);
}